// Round 6
// baseline (295.132 us; speedup 1.0000x reference)
//
#include <hip/hip_runtime.h>

typedef float f4 __attribute__((ext_vector_type(4)));
typedef float f16v __attribute__((ext_vector_type(16)));
typedef _Float16 hf;
typedef __fp16 fp16x2 __attribute__((ext_vector_type(2)));
typedef hf h4 __attribute__((ext_vector_type(4)));
typedef hf h8 __attribute__((ext_vector_type(8)));
typedef unsigned short ushort_t;
typedef unsigned int uint_t;
typedef uint_t u4 __attribute__((ext_vector_type(4)));

#define BATCH 8
#define CH 128
#define NPIX 4096
#define LOG2E 1.4426950408889634f

__device__ inline f16v mfma32h(h8 a, h8 b, f16v c) {
    return __builtin_amdgcn_mfma_f32_32x32x16_f16(a, b, c, 0, 0, 0);
}

__device__ inline uint_t pk2h(float a, float b) {  // pack 2 fp32 -> fp16x2 (RTZ), as u32
    fp16x2 pp = __builtin_amdgcn_cvt_pkrtz(a, b);
    union { fp16x2 v; uint_t u; } cv;
    cv.v = pp;
    return cv.u;
}

typedef __attribute__((address_space(3))) uint_t lds_uint;
typedef __attribute__((address_space(1))) const uint_t global_uint;
__device__ inline void dma16(const void* g, void* l) {
    __builtin_amdgcn_global_load_lds((global_uint*)g, (lds_uint*)l, 16, 0, 0);
}

// ---------------- weight transpose: wt[m][c][o] = W_m[o][c] ----------------
__global__ __launch_bounds__(256) void wtrans_kernel(const float* __restrict__ Wq,
                                                     const float* __restrict__ Wk,
                                                     const float* __restrict__ Wv,
                                                     float* __restrict__ wt) {
    int m = blockIdx.x;
    const float* W = (m == 0) ? Wq : (m == 1) ? Wk : Wv;
    float* o = wt + m * CH * CH;
    for (int idx = threadIdx.x; idx < CH * CH; idx += 256) {
        int r = idx >> 7;
        int c = idx & (CH - 1);
        o[c * CH + r] = W[idx];
    }
}

// ---------------- QKV projection -> fp16 ----------------
// Q: [b][n][c] hi+lo fp16 (scaled by log2e);  K: [b][n][c] fp16;  V: [b][c][n] fp16.
// grid: 3*8*64 blocks (64-px chunks), 256 threads; LDS 32 KB -> 5 blocks/CU.
__global__ __launch_bounds__(256) void qkv_kernel(const float* __restrict__ x1,
                                                  const float* __restrict__ x2,
                                                  const float* __restrict__ wt,
                                                  const float* __restrict__ bq,
                                                  const float* __restrict__ bk,
                                                  const float* __restrict__ bv,
                                                  hf* __restrict__ Qhi, hf* __restrict__ Qlo,
                                                  hf* __restrict__ Kf, hf* __restrict__ Vf) {
    __shared__ __align__(16) float Xs[CH * 64];  // 32 KB

    int bid = blockIdx.x;
    int m = bid >> 9;          // 0..2
    int rem = bid & 511;
    int b = rem & 7;
    int n0 = (rem >> 3) << 6;  // 64-px chunk

    const float* X = ((m == 0) ? x1 : x2) + (size_t)b * CH * NPIX;
    const float* WTm = wt + m * CH * CH;  // [c][o], o contiguous
    const float* bias = (m == 0) ? bq : (m == 1) ? bk : bv;

    int tid = threadIdx.x;
#pragma unroll
    for (int r = 0; r < 8; ++r) {
        int idx = r * 256 + tid;
        int c = idx >> 4;
        int p4 = (idx & 15) << 2;
        *(f4*)&Xs[c * 64 + p4] = *(const f4*)&X[(size_t)c * NPIX + n0 + p4];
    }
    __syncthreads();

    int tx = tid & 15;  // pixel quad: 4tx..4tx+3
    int ty = tid >> 4;  // channel oct: 8ty..8ty+7

    f4 a[8];
#pragma unroll
    for (int u = 0; u < 8; ++u) a[u] = f4{0.f, 0.f, 0.f, 0.f};

#pragma unroll 4
    for (int c = 0; c < CH; ++c) {
        f4 xv = *(const f4*)&Xs[c * 64 + 4 * tx];
        f4 wa = *(const f4*)&WTm[c * CH + 8 * ty];      // L1-broadcast across 16 lanes
        f4 wb = *(const f4*)&WTm[c * CH + 8 * ty + 4];
#pragma unroll
        for (int u = 0; u < 4; ++u) {
            a[u] += wa[u] * xv;
            a[4 + u] += wb[u] * xv;
        }
    }

    float bb[8];
#pragma unroll
    for (int u = 0; u < 8; ++u) bb[u] = bias[8 * ty + u];

    if (m == 0) {  // Q -> hi+lo, scaled by log2e
#pragma unroll
        for (int p = 0; p < 4; ++p) {
            size_t rowb = ((size_t)b * NPIX + n0 + 4 * tx + p) * CH + 8 * ty;
            h8 hi, lo;
#pragma unroll
            for (int u = 0; u < 8; ++u) {
                float v = (a[u][p] + bb[u]) * LOG2E;
                hf hb = (hf)v;
                hi[u] = hb;
                lo[u] = (hf)(v - (float)hb);
            }
            *(h8*)&Qhi[rowb] = hi;
            *(h8*)&Qlo[rowb] = lo;
        }
    } else if (m == 1) {  // K
#pragma unroll
        for (int p = 0; p < 4; ++p) {
            size_t rowb = ((size_t)b * NPIX + n0 + 4 * tx + p) * CH + 8 * ty;
            h8 hi;
#pragma unroll
            for (int u = 0; u < 8; ++u) hi[u] = (hf)(a[u][p] + bb[u]);
            *(h8*)&Kf[rowb] = hi;
        }
    } else {  // V -> [b][c][n]
#pragma unroll
        for (int u = 0; u < 8; ++u) {
            h4 hv;
#pragma unroll
            for (int p = 0; p < 4; ++p) hv[p] = (hf)(a[u][p] + bb[u]);
            *(h4*)&Vf[((size_t)b * CH + 8 * ty + u) * NPIX + n0 + 4 * tx] = hv;
        }
    }
}

// ---------------- fp16 MFMA flash attention, deferred-PV pipeline ----------------
// grid: 8*64 blocks, 256 threads; LDS 80 KB (K dbuf + V tri-buf) -> 2 blocks/CU.
// iter t: DMA(t+1) | PV(t-1) MFMA | S(t) MFMA | softmax(t) VALU | barrier
__global__ __launch_bounds__(256, 2) void attn_kernel(const hf* __restrict__ Qhi,
                                                      const hf* __restrict__ Qlo,
                                                      const hf* __restrict__ Kf,
                                                      const hf* __restrict__ Vf,
                                                      float* __restrict__ out) {
    __shared__ __align__(16) ushort_t smem[40960];  // 80 KB: K slots @0/8192, V slots @16384+s*8192

    int tid = threadIdx.x;
    int lane = tid & 63;
    int w = tid >> 6;
    int h = lane >> 5;
    int m32 = lane & 31;
    int qh = w >> 1, kh = w & 1;

    int b = blockIdx.x & 7;            // batch <-> XCD for K/V L2 locality
    int i0g = (blockIdx.x >> 3) << 6;  // 64-query tile
    int qrow = i0g + qh * 32 + m32;

    const hf* Qhb = Qhi + (size_t)b * NPIX * CH;
    const hf* Qlb = Qlo + (size_t)b * NPIX * CH;
    const hf* Kfb = Kf + (size_t)b * NPIX * CH;
    const hf* Vfb = Vf + (size_t)b * CH * NPIX;

    // Q B-frags (hi+lo) in registers for the whole loop
    h8 qfh[8], qfl[8];
#pragma unroll
    for (int kc = 0; kc < 8; ++kc) {
        size_t off = (size_t)qrow * CH + kc * 16 + h * 8;
        qfh[kc] = *(const h8*)&Qhb[off];
        qfl[kc] = *(const h8*)&Qlb[off];
    }

    // DMA source pointers (XOR swizzle folded into global address)
    const hf* pK[4];
    const hf* pV[4];
#pragma unroll
    for (int a = 0; a < 4; ++a) {
        int g = w * 4 + a;
        int rowk = g * 4 + (lane >> 4);
        int lck = (lane & 15) ^ (rowk & 15);
        pK[a] = Kfb + (size_t)rowk * CH + lck * 8;
        int rowv = g * 8 + (lane >> 3);
        int lcv = (lane & 7) ^ (rowv & 7);
        pV[a] = Vfb + (size_t)rowv * NPIX + lcv * 8;
    }

    // prologue: K(0)->slot0, V(0)->slot0
#pragma unroll
    for (int a = 0; a < 4; ++a) {
        dma16(pK[a], &smem[(w * 4 + a) * 512]);
        dma16(pV[a], &smem[16384 + (w * 4 + a) * 512]);
        pK[a] += 64 * CH;
        pV[a] += 64;
    }

    f16v accO[4];
#pragma unroll
    for (int ct = 0; ct < 4; ++ct)
#pragma unroll
        for (int r = 0; r < 16; ++r) accO[ct][r] = 0.f;
    float mprev = -1e30f, lsum = 0.f;
    h8 pbp[2];

    int krow = kh * 32 + m32;
    int pc2s[2];
#pragma unroll
    for (int g2 = 0; g2 < 2; ++g2) pc2s[g2] = (kh * 4 + g2 * 2 + h) ^ (m32 & 7);

    int vp = 2, vc = 0, vn = 1;  // V slot rotation: vp=V(t-1), vc=V(t), vn<-V(t+1)
    __syncthreads();

    for (int t = 0; t < 64; ++t) {
        if (t < 63) {
            int kn = (t + 1) & 1;
#pragma unroll
            for (int a = 0; a < 4; ++a) {
                dma16(pK[a], &smem[kn * 8192 + (w * 4 + a) * 512]);
                dma16(pV[a], &smem[16384 + vn * 8192 + (w * 4 + a) * 512]);
                pK[a] += 64 * CH;
                pV[a] += 64;
            }
        }

        // --- PV(t-1): O^T[c][q] += V(t-1) . P(t-1) (independent of everything above) ---
        if (t) {
            const ushort_t* vb = smem + 16384 + vp * 8192;
#pragma unroll
            for (int g2 = 0; g2 < 2; ++g2)
#pragma unroll
                for (int ct = 0; ct < 4; ++ct) {
                    h8 av = *(const h8*)&vb[(ct * 32 + m32) * 64 + pc2s[g2] * 8];
                    accO[ct] = mfma32h(av, pbp[g2], accO[ct]);
                }
        }

        // --- S^T(t)[key][query] = K . (Qh+Ql)^T, 2-pass fp16 (log2 units) ---
        const ushort_t* kb = smem + (t & 1) * 8192;
        f16v acc;
#pragma unroll
        for (int r = 0; r < 16; ++r) acc[r] = 0.f;
#pragma unroll
        for (int kc = 0; kc < 8; ++kc) {
            int pA = (kc * 2 + h) ^ (m32 & 15);
            h8 ahi = *(const h8*)&kb[krow * 128 + pA * 8];
            acc = mfma32h(ahi, qfh[kc], acc);
            acc = mfma32h(ahi, qfl[kc], acc);
        }

        // --- softmax(t), wave-private, quantized max (step 4, base-2) ---
        float mx[8];
#pragma unroll
        for (int r = 0; r < 8; ++r) mx[r] = fmaxf(acc[r], acc[r + 8]);
#pragma unroll
        for (int r = 0; r < 4; ++r) mx[r] = fmaxf(mx[r], mx[r + 4]);
        float tmax = fmaxf(fmaxf(mx[0], mx[1]), fmaxf(mx[2], mx[3]));
        tmax = fmaxf(tmax, __shfl_xor(tmax, 32));
        float qm = 4.0f * ceilf(tmax * 0.25f);
        if (__any(qm > mprev)) {  // rare after warm-up
            float mnew = fmaxf(mprev, qm);
            float alpha = exp2f(mprev - mnew);
            lsum *= alpha;
#pragma unroll
            for (int ct = 0; ct < 4; ++ct)
#pragma unroll
                for (int r = 0; r < 16; ++r) accO[ct][r] *= alpha;
            mprev = mnew;
        }

        float p[16];
#pragma unroll
        for (int r = 0; r < 16; ++r) p[r] = exp2f(acc[r] - mprev);
        float ps[8];
#pragma unroll
        for (int r = 0; r < 8; ++r) ps[r] = p[r] + p[r + 8];
#pragma unroll
        for (int r = 0; r < 4; ++r) ps[r] += ps[r + 4];
        float psum = (ps[0] + ps[1]) + (ps[2] + ps[3]);
        psum += __shfl_xor(psum, 32);
        lsum += psum;

        // pack P(t) into PV B-frags for next iteration
        uint_t pk[8], rv[8];
#pragma unroll
        for (int t2 = 0; t2 < 8; ++t2) pk[t2] = pk2h(p[2 * t2], p[2 * t2 + 1]);
#pragma unroll
        for (int t2 = 0; t2 < 8; ++t2) rv[t2] = (uint_t)__shfl_xor((int)pk[t2], 32);
#pragma unroll
        for (int g2 = 0; g2 < 2; ++g2) {
            u4 fv;
            fv[0] = h ? rv[g2 * 4 + 2] : pk[g2 * 4 + 0];
            fv[1] = h ? rv[g2 * 4 + 3] : pk[g2 * 4 + 1];
            fv[2] = h ? pk[g2 * 4 + 2] : rv[g2 * 4 + 0];
            fv[3] = h ? pk[g2 * 4 + 3] : rv[g2 * 4 + 1];
            __builtin_memcpy(&pbp[g2], &fv, 16);
        }

        __syncthreads();  // drains DMA(t+1); all reads of K(t)/V(t-1) done
        int tv = vp; vp = vc; vc = vn; vn = tv;
    }

    // --- drain: PV(63) ---
    {
        const ushort_t* vb = smem + 16384 + vp * 8192;
#pragma unroll
        for (int g2 = 0; g2 < 2; ++g2)
#pragma unroll
            for (int ct = 0; ct < 4; ++ct) {
                h8 av = *(const h8*)&vb[(ct * 32 + m32) * 64 + pc2s[g2] * 8];
                accO[ct] = mfma32h(av, pbp[g2], accO[ct]);
            }
    }

    // --- epilogue: merge key-half waves (base-2), store out[b][c][i] ---
    float* scr = (float*)smem;
    if (h == 0) {
        scr[kh * 64 + qh * 32 + m32] = mprev;
        scr[128 + kh * 64 + qh * 32 + m32] = lsum;
    }
    __syncthreads();
    float mo = scr[(1 - kh) * 64 + qh * 32 + m32];
    float lo2 = scr[128 + (1 - kh) * 64 + qh * 32 + m32];
    float mf = fmaxf(mprev, mo);
    float fs = exp2f(mprev - mf);
    float fo = exp2f(mo - mf);
    float rinv = fs / (fs * lsum + fo * lo2);

    float* mrg = (float*)(smem + 2048);  // bytes 4096..36864, disjoint from scr
    if (kh == 1) {
#pragma unroll
        for (int ct = 0; ct < 4; ++ct)
#pragma unroll
            for (int r = 0; r < 16; ++r) {
                int ch = ct * 32 + (r & 3) + 8 * (r >> 2) + 4 * h;
                mrg[qh * 4096 + ch * 32 + m32] = accO[ct][r] * rinv;
            }
    }
    __syncthreads();
    if (kh == 0) {
        float* O = out + (size_t)b * CH * NPIX;
#pragma unroll
        for (int ct = 0; ct < 4; ++ct)
#pragma unroll
            for (int r = 0; r < 16; ++r) {
                int ch = ct * 32 + (r & 3) + 8 * (r >> 2) + 4 * h;
                O[(size_t)ch * NPIX + i0g + qh * 32 + m32] =
                    accO[ct][r] * rinv + mrg[qh * 4096 + ch * 32 + m32];
            }
    }
}

extern "C" void kernel_launch(void* const* d_in, const int* in_sizes, int n_in,
                              void* d_out, int out_size, void* d_ws, size_t ws_size,
                              hipStream_t stream) {
    const float* x1 = (const float*)d_in[0];
    const float* x2 = (const float*)d_in[1];
    const float* Wq = (const float*)d_in[2];
    const float* bq = (const float*)d_in[3];
    const float* Wk = (const float*)d_in[4];
    const float* bk = (const float*)d_in[5];
    const float* Wv = (const float*)d_in[6];
    const float* bv = (const float*)d_in[7];
    float* outp = (float*)d_out;

    const size_t N = (size_t)BATCH * NPIX * CH;
    hf* Qhi = (hf*)d_ws;
    hf* Qlo = Qhi + N;
    hf* Kf = Qhi + 2 * N;
    hf* Vf = Qhi + 3 * N;
    float* wt = (float*)(Qhi + 4 * N);

    wtrans_kernel<<<3, 256, 0, stream>>>(Wq, Wk, Wv, wt);
    qkv_kernel<<<3 * BATCH * (NPIX / 64), 256, 0, stream>>>(x1, x2, wt, bq, bk, bv,
                                                            Qhi, Qlo, Kf, Vf);
    attn_kernel<<<BATCH * (NPIX / 64), 256, 0, stream>>>(Qhi, Qlo, Kf, Vf, outp);
}